// Round 10
// baseline (204.219 us; speedup 1.0000x reference)
//
#include <hip/hip_runtime.h>
#include <math.h>

// out layout: [ray_origins (N*M*3 f32)] [ray_dirs (N*M*3 f32)]
//
// Structure identical to the harness-verified 196.9us kernel (768 blocks of
// 256 threads per camera region, one float4 per stream per thread, wave
// stores perfectly lane-contiguous 64 x 16B = 1KB).
//
// SINGLE change this round: both output stores use
// __builtin_nontemporal_store. Evidence: rocprof shows the harness fill
// writes 768 MiB at 6.6 TB/s with FETCH_SIZE ~14 KB (no read-for-ownership),
// while our kernel's effective write BW was only ~2.65 TB/s. Theory: plain
// global_store_dwordx4 triggers L2 write-allocate (RFO) -> HBM fetches each
// line before writing it, doubling traffic (384 MiB moved, 5.3 TB/s actual
// = at the ceiling). nt stores skip the allocate like the runtime fill does.
// Predicted: kernel FETCH_SIZE ~190MB -> ~KB, kernel ~76us -> ~35-45us.
typedef float f32x4 __attribute__((ext_vector_type(4)));

__global__ __launch_bounds__(256) void ray_sampler_contig(
    const float* __restrict__ c2w,   // N*16 fp32, row-major 4x4
    const float* __restrict__ intr,  // N*9 fp32, row-major 3x3
    float* __restrict__ out,
    int blocks_per_cam,   // (M*3/4) / 256 = 768
    int resShift,         // log2(res)
    float inv_res,
    size_t dir_off)       // N*M*3 floats
{
    // wave-uniform camera index
    const unsigned n   = (unsigned)blockIdx.x / (unsigned)blocks_per_cam;
    const unsigned blk = (unsigned)blockIdx.x - n * (unsigned)blocks_per_cam;
    const unsigned q   = blk * 256u + threadIdx.x;      // float4 idx within camera region
    const unsigned f4_per_cam = (unsigned)blocks_per_cam * 256u;

    const float* C = c2w + n * 16;   // uniform -> s_load
    const float* K = intr + n * 9;   // uniform -> s_load

    const float r00 = C[0], r01 = C[1], r02 = C[2], ox = C[3];
    const float r10 = C[4], r11 = C[5], r12 = C[6], oy = C[7];
    const float r20 = C[8], r21 = C[9], r22 = C[10], oz = C[11];
    const float fx = K[0], sk = K[1], cx = K[2];
    const float fy = K[4], cy = K[5];

    const float inv_fx = 1.0f / fx;   // uniform, once
    const float inv_fy = 1.0f / fy;

    const unsigned f0    = q * 4u;        // float offset within camera region
    const unsigned p0    = f0 / 3u;       // first pixel spanned (magic-mul)
    const unsigned phase = f0 - p0 * 3u;  // 0,1,2
    const unsigned rmask = (1u << resShift) - 1u;

    const size_t t = (size_t)n * f4_per_cam + q;   // global float4 index

    // ---- origins: uniform values + per-lane phase, compile-time selects only
    {
        const float ax = (phase == 0u) ? ox : ((phase == 1u) ? oy : oz);
        const float ay = (phase == 0u) ? oy : ((phase == 1u) ? oz : ox);
        const float az = (phase == 0u) ? oz : ((phase == 1u) ? ox : oy);
        const f32x4 vo = {ax, ay, az, ax};             // w==x all phases
        __builtin_nontemporal_store(vo, reinterpret_cast<f32x4*>(out) + t);
    }

    // ---- normalized ray dirs for the two pixels this float4 spans
    float d0x, d0y, d0z, d1x, d1y, d1z;
    #pragma unroll
    for (int s = 0; s < 2; ++s) {
        const unsigned p = p0 + (unsigned)s;   // stays inside this camera (region%4==0)
        const unsigned i = p >> resShift;      // row (y)
        const unsigned j = p & rmask;          // col (x)

        const float y_cam  = ((float)i + 0.5f) * inv_res;
        const float ycc    = (y_cam - cy) * inv_fy;
        const float y_lift = -ycc;
        const float xc_off = -cx - sk * ycc;
        const float x_cam  = ((float)j + 0.5f) * inv_res;
        const float x_lift = (x_cam + xc_off) * inv_fx;

        const float ux = fmaf(r00, x_lift, fmaf(r01, y_lift, -r02));
        const float uy = fmaf(r10, x_lift, fmaf(r11, y_lift, -r12));
        const float uz = fmaf(r20, x_lift, fmaf(r21, y_lift, -r22));
        const float ss  = fmaf(ux, ux, fmaf(uy, uy, uz * uz));
        const float inv = rsqrtf(fmaxf(ss, 1e-24f));   // matches max(norm, 1e-12)

        if (s == 0) { d0x = ux * inv; d0y = uy * inv; d0z = uz * inv; }
        else        { d1x = ux * inv; d1y = uy * inv; d1z = uz * inv; }
    }

    f32x4 vd;
    vd.x = (phase == 0u) ? d0x : ((phase == 1u) ? d0y : d0z);
    vd.y = (phase == 0u) ? d0y : ((phase == 1u) ? d0z : d1x);
    vd.z = (phase == 0u) ? d0z : ((phase == 1u) ? d1x : d1y);
    vd.w = (phase == 0u) ? d1x : ((phase == 1u) ? d1y : d1z);
    __builtin_nontemporal_store(vd, reinterpret_cast<f32x4*>(out + dir_off) + t);
}

extern "C" void kernel_launch(void* const* d_in, const int* in_sizes, int n_in,
                              void* d_out, int out_size, void* d_ws, size_t ws_size,
                              hipStream_t stream) {
    const float* c2w  = (const float*)d_in[0];   // fp32, N x 4 x 4
    const float* intr = (const float*)d_in[1];   // fp32, N x 3 x 3
    float* out = (float*)d_out;                  // fp32

    const int N = in_sizes[0] / 16;                                  // 32
    const long long M = (long long)out_size / (6LL * (long long)N);  // 262144
    const int res = (int)(sqrt((double)M) + 0.5);                    // 512

    int resShift = 0; while ((1 << resShift) < res) ++resShift;      // 9

    const long long F    = (long long)N * M * 3LL;   // floats per region
    const int f4_per_cam = (int)(M * 3LL / 4LL);     // 196608
    const int blocks_per_cam = f4_per_cam / 256;     // 768 (exact)
    const int grid = N * blocks_per_cam;             // 24576
    const size_t dir_off = (size_t)F;

    ray_sampler_contig<<<grid, 256, 0, stream>>>(c2w, intr, out,
                                                 blocks_per_cam, resShift,
                                                 1.0f / (float)res, dir_off);
}

// Round 11
// 196.090 us; speedup vs baseline: 1.0415x; 1.0415x over previous
//
#include <hip/hip_runtime.h>
#include <math.h>

// out layout: [ray_origins (N*M*3 f32)] [ray_dirs (N*M*3 f32)]
//
// Fill-shaped deep-store restructure. Evidence: harness fill sustains
// 6.6 TB/s (FETCH ~0) with few blocks and many back-to-back stores per
// wave; our 1-float4-per-thread kernel got only ~2.65 TB/s effective
// (~76us for 201 MB) despite identical per-instruction coalescing, and
// nt-stores were neutral (RFO theory refuted). Theory: limit is per-wave
// in-flight store depth + wave churn (2 stores then endpgm), not bytes.
//
// This version: 96 blocks per camera, each block owns 2048 consecutive
// float4s per stream; thread t stores q = chunk + k*256 + t for k=0..7.
// Every store instruction is still a lane-contiguous 1KB burst. Each wave
// issues 8 independent origin stores up front, then 8 dir stores as
// computed: 16 KB per wave vs 2 KB before. Plain stores (round-7 type).
typedef float f32x4 __attribute__((ext_vector_type(4)));

__global__ __launch_bounds__(256) void ray_sampler_deep(
    const float* __restrict__ c2w,   // N*16 fp32, row-major 4x4
    const float* __restrict__ intr,  // N*9 fp32, row-major 3x3
    float* __restrict__ out,
    int blocks_per_cam,   // (M*3/4) / 2048 = 96
    int resShift,         // log2(res)
    float inv_res,
    size_t dir_off)       // N*M*3 floats
{
    // block-uniform camera index -> camera constants via s_load
    const unsigned n   = (unsigned)blockIdx.x / (unsigned)blocks_per_cam;
    const unsigned blk = (unsigned)blockIdx.x - n * (unsigned)blocks_per_cam;
    const unsigned f4_per_cam = (unsigned)blocks_per_cam * 2048u;

    const float* C = c2w + n * 16;
    const float* K = intr + n * 9;

    const float r00 = C[0], r01 = C[1], r02 = C[2], ox = C[3];
    const float r10 = C[4], r11 = C[5], r12 = C[6], oy = C[7];
    const float r20 = C[8], r21 = C[9], r22 = C[10], oz = C[11];
    const float fx = K[0], sk = K[1], cx = K[2];
    const float fy = K[4], cy = K[5];

    const float inv_fx = 1.0f / fx;
    const float inv_fy = 1.0f / fy;
    const unsigned rmask = (1u << resShift) - 1u;

    const unsigned q0  = blk * 2048u + threadIdx.x;       // first float4 idx in region
    const unsigned f00 = q0 * 4u;                         // its float offset
    const size_t   t0  = (size_t)n * f4_per_cam + q0;     // global float4 index

    f32x4* o4 = reinterpret_cast<f32x4*>(out);
    f32x4* d4 = reinterpret_cast<f32x4*>(out + dir_off);

    // ---- burst 1: eight independent origin stores (cheap selects only)
    #pragma unroll
    for (int k = 0; k < 8; ++k) {
        const unsigned f0 = f00 + 1024u * (unsigned)k;    // compile-time addend
        const unsigned p0 = f0 / 3u;                      // magic-mul
        const unsigned ph = f0 - p0 * 3u;                 // 0,1,2
        const float ax = (ph == 0u) ? ox : ((ph == 1u) ? oy : oz);
        const float ay = (ph == 0u) ? oy : ((ph == 1u) ? oz : ox);
        const float az = (ph == 0u) ? oz : ((ph == 1u) ? ox : oy);
        const f32x4 vo = {ax, ay, az, ax};                // w==x for all phases
        o4[t0 + 256u * (unsigned)k] = vo;
    }

    // ---- burst 2: eight dir float4s, stored as computed (independent stores)
    #pragma unroll
    for (int k = 0; k < 8; ++k) {
        const unsigned f0 = f00 + 1024u * (unsigned)k;
        const unsigned p0 = f0 / 3u;
        const unsigned ph = f0 - p0 * 3u;

        float d0x, d0y, d0z, d1x, d1y, d1z;
        #pragma unroll
        for (int s = 0; s < 2; ++s) {
            const unsigned p = p0 + (unsigned)s;   // in-camera: max p0+1 = M-1
            const unsigned i = p >> resShift;      // row (y)
            const unsigned j = p & rmask;          // col (x)

            const float y_cam  = ((float)i + 0.5f) * inv_res;
            const float ycc    = (y_cam - cy) * inv_fy;
            const float y_lift = -ycc;
            const float xc_off = -cx - sk * ycc;
            const float x_cam  = ((float)j + 0.5f) * inv_res;
            const float x_lift = (x_cam + xc_off) * inv_fx;

            const float ux = fmaf(r00, x_lift, fmaf(r01, y_lift, -r02));
            const float uy = fmaf(r10, x_lift, fmaf(r11, y_lift, -r12));
            const float uz = fmaf(r20, x_lift, fmaf(r21, y_lift, -r22));
            const float ss  = fmaf(ux, ux, fmaf(uy, uy, uz * uz));
            const float inv = rsqrtf(fmaxf(ss, 1e-24f));   // = 1/max(norm,1e-12)

            if (s == 0) { d0x = ux * inv; d0y = uy * inv; d0z = uz * inv; }
            else        { d1x = ux * inv; d1y = uy * inv; d1z = uz * inv; }
        }

        f32x4 vd;
        vd.x = (ph == 0u) ? d0x : ((ph == 1u) ? d0y : d0z);
        vd.y = (ph == 0u) ? d0y : ((ph == 1u) ? d0z : d1x);
        vd.z = (ph == 0u) ? d0z : ((ph == 1u) ? d1x : d1y);
        vd.w = (ph == 0u) ? d1x : ((ph == 1u) ? d1y : d1z);
        d4[t0 + 256u * (unsigned)k] = vd;
    }
}

extern "C" void kernel_launch(void* const* d_in, const int* in_sizes, int n_in,
                              void* d_out, int out_size, void* d_ws, size_t ws_size,
                              hipStream_t stream) {
    const float* c2w  = (const float*)d_in[0];   // fp32, N x 4 x 4
    const float* intr = (const float*)d_in[1];   // fp32, N x 3 x 3
    float* out = (float*)d_out;                  // fp32

    const int N = in_sizes[0] / 16;                                  // 32
    const long long M = (long long)out_size / (6LL * (long long)N);  // 262144
    const int res = (int)(sqrt((double)M) + 0.5);                    // 512

    int resShift = 0; while ((1 << resShift) < res) ++resShift;      // 9

    const long long F    = (long long)N * M * 3LL;   // floats per region
    const int f4_per_cam = (int)(M * 3LL / 4LL);     // 196608
    const int blocks_per_cam = f4_per_cam / 2048;    // 96 (exact)
    const int grid = N * blocks_per_cam;             // 3072
    const size_t dir_off = (size_t)F;

    ray_sampler_deep<<<grid, 256, 0, stream>>>(c2w, intr, out,
                                               blocks_per_cam, resShift,
                                               1.0f / (float)res, dir_off);
}